// Round 8
// baseline (165.139 us; speedup 1.0000x reference)
//
#include <hip/hip_runtime.h>
#include <stdint.h>

// Problem dims: x(4,2048,512) W1(512,1024) b1(1024) Wq(1024,1024) A=16 — fp32 in, fp32 out
constexpr int BATCH = 4;
constexpr int SEQ   = 2048;
constexpr int DIN   = 512;
constexpr int DH    = 1024;
constexpr int BS    = BATCH * SEQ;  // 8192
constexpr int AP    = 32;           // attn positions per block
constexpr int AW    = 64;           // attn window rows (AP + 2*16)

typedef float  floatx4 __attribute__((ext_vector_type(4)));
typedef short  bf16x8  __attribute__((ext_vector_type(8)));

static __device__ __forceinline__ unsigned short f2bf(float f) {
  union { float f; unsigned u; } v; v.f = f;
  unsigned r = (v.u + 0x7fffu + ((v.u >> 16) & 1u)) >> 16;  // RNE
  return (unsigned short)r;
}

// async global->LDS, 16B per lane; LDS dest is wave-uniform base + lane*16
static __device__ __forceinline__ void gld_lds16(const unsigned short* g, const short* l) {
  typedef const __attribute__((address_space(1))) void* gvp;
  typedef __attribute__((address_space(3))) void* lvp;
  __builtin_amdgcn_global_load_lds((gvp)(uintptr_t)g, (lvp)(unsigned)(uintptr_t)l, 16, 0, 0);
}

// ---------------- fused weight transposes: W1(512x1024) and Wq(1024x1024) -> bf16 ^T ----
// grid.y in [0,48): y<16 -> W1 tile row, else Wq tile row. grid.x = 32 col-tiles.
__global__ __launch_bounds__(256) void transpose_w_k(const float* __restrict__ W1,
                                                     const float* __restrict__ Wq,
                                                     unsigned short* __restrict__ w1t,
                                                     unsigned short* __restrict__ wqt) {
  __shared__ float t[32][33];
  const bool isW1 = blockIdx.y < 16;
  const float* in = isW1 ? W1 : Wq;
  unsigned short* out = isW1 ? w1t : wqt;
  const int R = isW1 ? DIN : DH;  // rows of source
  const int C = DH;
  const int r0 = (isW1 ? blockIdx.y : (blockIdx.y - 16)) * 32;
  const int c0 = blockIdx.x * 32;
  const int tx = threadIdx.x & 31, ty = threadIdx.x >> 5;  // 32 x 8
  for (int i = ty; i < 32; i += 8) t[i][tx] = in[(size_t)(r0 + i) * C + c0 + tx];
  __syncthreads();
  for (int i = ty; i < 32; i += 8) out[(size_t)(c0 + i) * R + r0 + tx] = f2bf(t[tx][i]);
}

// ---------------- GEMM1: h = relu(x @ W1 + b1), fused fp32->bf16 A-staging --------------
// 128x128 tile, BK=32. Grid: blockIdx.x = M-tile so same-M blocks share an XCD (L2 reuse).
// Emits h row-major (hb) and transposed (hbT).
__global__ __launch_bounds__(256) void gemm1_k(const float* __restrict__ X,
                                               const unsigned short* __restrict__ Bt,
                                               const float* __restrict__ bias,
                                               unsigned short* __restrict__ outB,
                                               unsigned short* __restrict__ outBT) {
  const int M = BS, N = DH, K = DIN;
  __shared__ __align__(16) short As[128 * 32];
  __shared__ __align__(16) short Bs[128 * 32];
  const int tid  = threadIdx.x;
  const int m0   = blockIdx.x * 128, n0 = blockIdx.y * 128;
  const int wv   = tid >> 6, lane = tid & 63;
  const int wm   = (wv >> 1) * 64, wn = (wv & 1) * 64;
  const int l16  = lane & 15, quad = lane >> 4;

  // A staging: thread covers row ar = tid>>1, 16 fp32 starting at col (tid&1)*16
  const int ar = tid >> 1, acol = (tid & 1) * 16;
  const float* gX = X + (size_t)(m0 + ar) * K + acol;
  short* lA = &As[ar * 32 + acol];
  // B staging via global_load_lds (wave wv covers Bs rows wv*32..wv*32+31)
  const int ra = lane >> 2, ca = (lane & 3) * 8;
  const unsigned short* gB0 = Bt + (size_t)(n0 + wv * 32 + ra) * K + ca;
  const unsigned short* gB1 = Bt + (size_t)(n0 + wv * 32 + 16 + ra) * K + ca;
  const short* lB0 = &Bs[wv * 1024];
  const short* lB1 = &Bs[wv * 1024 + 512];

  floatx4 acc[4][4];
  for (int i = 0; i < 4; i++)
    for (int j = 0; j < 4; j++) acc[i][j] = {0.f, 0.f, 0.f, 0.f};

  for (int ks = 0; ks < K / 32; ++ks) {
    float4 x0 = ((const float4*)gX)[0], x1 = ((const float4*)gX)[1];
    float4 x2 = ((const float4*)gX)[2], x3 = ((const float4*)gX)[3];
    gX += 32;
    // convert OUTSIDE the barrier-to-barrier critical section (depends only on loads)
    __align__(16) unsigned short cv[16];
    cv[0] = f2bf(x0.x); cv[1] = f2bf(x0.y); cv[2]  = f2bf(x0.z); cv[3]  = f2bf(x0.w);
    cv[4] = f2bf(x1.x); cv[5] = f2bf(x1.y); cv[6]  = f2bf(x1.z); cv[7]  = f2bf(x1.w);
    cv[8] = f2bf(x2.x); cv[9] = f2bf(x2.y); cv[10] = f2bf(x2.z); cv[11] = f2bf(x2.w);
    cv[12] = f2bf(x3.x); cv[13] = f2bf(x3.y); cv[14] = f2bf(x3.z); cv[15] = f2bf(x3.w);
    __syncthreads();  // prev iter LDS reads done
    gld_lds16(gB0, lB0); gld_lds16(gB1, lB1);
    gB0 += 32; gB1 += 32;
    ((uint4*)lA)[0] = ((uint4*)cv)[0];
    ((uint4*)lA)[1] = ((uint4*)cv)[1];
    __syncthreads();  // drains vmcnt + lgkmcnt before barrier
    bf16x8 af[4], bfr[4];
    for (int i = 0; i < 4; i++)
      af[i] = *(const bf16x8*)&As[(wm + i * 16 + l16) * 32 + quad * 8];
    for (int j = 0; j < 4; j++)
      bfr[j] = *(const bf16x8*)&Bs[(wn + j * 16 + l16) * 32 + quad * 8];
    for (int i = 0; i < 4; i++)
      for (int j = 0; j < 4; j++)
        acc[i][j] = __builtin_amdgcn_mfma_f32_16x16x32_bf16(af[i], bfr[j], acc[i][j], 0, 0, 0);
  }

  // epilogue: C row = m0+wm+i*16+quad*4+r, col = n0+wn+j*16+l16 (m89-verified C/D layout)
  for (int j = 0; j < 4; j++) {
    const int col = n0 + wn + j * 16 + l16;
    const float bv = bias[col];
    for (int i = 0; i < 4; i++) {
      const int rowb = m0 + wm + i * 16 + quad * 4;
      float v[4];
      for (int r = 0; r < 4; r++) v[r] = fmaxf(acc[i][j][r] + bv, 0.f);
      for (int r = 0; r < 4; r++) outB[(size_t)(rowb + r) * N + col] = f2bf(v[r]);
      ushort4 o4; o4.x = f2bf(v[0]); o4.y = f2bf(v[1]); o4.z = f2bf(v[2]); o4.w = f2bf(v[3]);
      *(ushort4*)(outBT + (size_t)col * M + rowb) = o4;  // transposed copy for attn PV
    }
  }
}

// ---------------- GEMM2: q = h @ Wq (bf16 A and B, both staged via global_load_lds) ------
__global__ __launch_bounds__(256) void gemm2_k(const unsigned short* __restrict__ Ab,
                                               const unsigned short* __restrict__ Bt,
                                               unsigned short* __restrict__ outB) {
  const int N = DH, K = DH;
  __shared__ __align__(16) short As[128 * 32];
  __shared__ __align__(16) short Bs[128 * 32];
  const int tid  = threadIdx.x;
  const int m0   = blockIdx.x * 128, n0 = blockIdx.y * 128;  // x = M-tile (XCD streaming)
  const int wv   = tid >> 6, lane = tid & 63;
  const int wm   = (wv >> 1) * 64, wn = (wv & 1) * 64;
  const int l16  = lane & 15, quad = lane >> 4;

  const int ra = lane >> 2, ca = (lane & 3) * 8;
  const unsigned short* gA0 = Ab + (size_t)(m0 + wv * 32 + ra) * K + ca;
  const unsigned short* gA1 = Ab + (size_t)(m0 + wv * 32 + 16 + ra) * K + ca;
  const unsigned short* gB0 = Bt + (size_t)(n0 + wv * 32 + ra) * K + ca;
  const unsigned short* gB1 = Bt + (size_t)(n0 + wv * 32 + 16 + ra) * K + ca;
  const short* lA0 = &As[wv * 1024];
  const short* lA1 = &As[wv * 1024 + 512];
  const short* lB0 = &Bs[wv * 1024];
  const short* lB1 = &Bs[wv * 1024 + 512];

  floatx4 acc[4][4];
  for (int i = 0; i < 4; i++)
    for (int j = 0; j < 4; j++) acc[i][j] = {0.f, 0.f, 0.f, 0.f};

  for (int ks = 0; ks < K / 32; ++ks) {
    __syncthreads();
    gld_lds16(gA0, lA0); gld_lds16(gA1, lA1);
    gld_lds16(gB0, lB0); gld_lds16(gB1, lB1);
    gA0 += 32; gA1 += 32; gB0 += 32; gB1 += 32;
    __syncthreads();
    bf16x8 af[4], bfr[4];
    for (int i = 0; i < 4; i++)
      af[i] = *(const bf16x8*)&As[(wm + i * 16 + l16) * 32 + quad * 8];
    for (int j = 0; j < 4; j++)
      bfr[j] = *(const bf16x8*)&Bs[(wn + j * 16 + l16) * 32 + quad * 8];
    for (int i = 0; i < 4; i++)
      for (int j = 0; j < 4; j++)
        acc[i][j] = __builtin_amdgcn_mfma_f32_16x16x32_bf16(af[i], bfr[j], acc[i][j], 0, 0, 0);
  }

  for (int j = 0; j < 4; j++) {
    const int col = n0 + wn + j * 16 + l16;
    for (int i = 0; i < 4; i++) {
      const int rowb = m0 + wm + i * 16 + quad * 4;
      for (int r = 0; r < 4; r++)
        outB[(size_t)(rowb + r) * N + col] = f2bf(acc[i][j][r]);
    }
  }
}

// ---------------- barrier-light MFMA banded attention ----------------
// Block: 512 threads (8 waves), AP=32 positions, window AW=64 rows, 2 barriers total.
// QK: fragments straight from global. PV transposed: each wave owns 8 dh-tiles, loads the
// hbT A-fragment ONCE and multiplies by both pos-half P fragments (halves hbT traffic).
__global__ __launch_bounds__(512) void attn_mfma_k(const unsigned short* __restrict__ hb,
                                                   const unsigned short* __restrict__ hbT,
                                                   const unsigned short* __restrict__ qb,
                                                   float* __restrict__ out) {
  __shared__ float Sf[32 * 64];                // raw scores
  __shared__ __align__(16) short Ps[32 * 72];  // softmax weights, row=pos, col=window k

  const int tid  = threadIdx.x;
  const int wave = tid >> 6, lane = tid & 63;
  const int l16  = lane & 15, quad = lane >> 4;
  const int p0   = blockIdx.x * AP;
  const int s0   = p0 & (SEQ - 1);

  for (int i = tid; i < 32 * 72 / 2; i += 512) ((unsigned*)Ps)[i] = 0;

  // ---------- QK: S[32x64], wave -> tile (mt = wave>>2, nt = wave&3) ----------
  {
    const int mt = wave >> 2, nt = wave & 3;
    const unsigned short* qp = qb + (size_t)(p0 + mt * 16 + l16) * DH + quad * 8;
    const int hrow = s0 - 16 + nt * 16 + l16;          // window row (per-lane)
    const bool hv = (hrow >= 0) && (hrow < SEQ);
    const unsigned short* hp = hb + (long long)(p0 - 16 + nt * 16 + l16) * DH + quad * 8;

    floatx4 ac[4] = {{0,0,0,0},{0,0,0,0},{0,0,0,0},{0,0,0,0}};
    const bf16x8 hz = {0,0,0,0,0,0,0,0};
    #pragma unroll
    for (int it = 0; it < 32; ++it) {                  // K = 1024
      bf16x8 qa = *(const bf16x8*)(qp + it * 32);
      bf16x8 ha = hz;
      if (hv) ha = *(const bf16x8*)(hp + it * 32);
      ac[it & 3] = __builtin_amdgcn_mfma_f32_16x16x32_bf16(qa, ha, ac[it & 3], 0, 0, 0);
    }
    floatx4 s4;
    for (int r = 0; r < 4; r++)
      s4[r] = (ac[0][r] + ac[1][r]) + (ac[2][r] + ac[3][r]);
    for (int r = 0; r < 4; r++)
      Sf[(mt * 16 + quad * 4 + r) * 64 + nt * 16 + l16] = s4[r] * (1.f / 32.f);
  }
  __syncthreads();

  // ---------- softmax over the 33 band entries jj = row..row+32 ----------
  {
    const int row = tid >> 4, k = tid & 15;  // 16 threads per row
    const float v0 = Sf[row * 64 + row + k];
    const float v1 = Sf[row * 64 + row + k + 16];
    const float v2 = (k == 0) ? Sf[row * 64 + row + 32] : -1e30f;
    float mx = fmaxf(v0, fmaxf(v1, v2));
    for (int off = 1; off < 16; off <<= 1) mx = fmaxf(mx, __shfl_xor(mx, off, 64));
    const float e0 = __expf(v0 - mx), e1 = __expf(v1 - mx);
    const float e2 = (k == 0) ? __expf(v2 - mx) : 0.f;
    float sum = e0 + e1 + e2;
    for (int off = 1; off < 16; off <<= 1) sum += __shfl_xor(sum, off, 64);
    const float inv = 1.f / sum;
    Ps[row * 72 + row + k] = f2bf(e0 * inv);
    Ps[row * 72 + row + k + 16] = f2bf(e1 * inv);
    if (k == 0) Ps[row * 72 + row + 32] = f2bf(e2 * inv);
  }
  __syncthreads();

  // ---------- PV (transposed): D[dh, pos] = Hwin^T @ P^T, both pos halves per wave ------
  {
    const bf16x8 pb00 = *(const bf16x8*)&Ps[(l16) * 72 + quad * 8];        // nt2=0, k 0..31
    const bf16x8 pb01 = *(const bf16x8*)&Ps[(l16) * 72 + 32 + quad * 8];   // nt2=0, k 32..63
    const bf16x8 pb10 = *(const bf16x8*)&Ps[(16 + l16) * 72 + quad * 8];   // nt2=1
    const bf16x8 pb11 = *(const bf16x8*)&Ps[(16 + l16) * 72 + 32 + quad * 8];

    int lo = 16 - s0; if (lo < 0) lo = 0;              // valid window-k range [lo,hi)
    int hi = SEQ + 16 - s0; if (hi > AW) hi = AW;
    const bool interior = (lo == 0) && (hi == AW);

    #pragma unroll
    for (int i = 0; i < 8; ++i) {
      const int mt2 = wave * 8 + i;  // dh tile (0..63)
      const unsigned short* ap = hbT + (size_t)(mt2 * 16 + l16) * BS + (p0 - 16) + quad * 8;
      bf16x8 aa0 = *(const bf16x8*)(ap);
      bf16x8 aa1 = *(const bf16x8*)(ap + 32);
      if (!interior) {
        #pragma unroll
        for (int j = 0; j < 8; j++) {
          const int k = quad * 8 + j;
          if (k < lo || k >= hi) aa0[j] = 0;
          if (k + 32 < lo || k + 32 >= hi) aa1[j] = 0;
        }
      }
      floatx4 o0 = {0.f, 0.f, 0.f, 0.f}, o1 = {0.f, 0.f, 0.f, 0.f};
      o0 = __builtin_amdgcn_mfma_f32_16x16x32_bf16(aa0, pb00, o0, 0, 0, 0);
      o0 = __builtin_amdgcn_mfma_f32_16x16x32_bf16(aa1, pb01, o0, 0, 0, 0);
      o1 = __builtin_amdgcn_mfma_f32_16x16x32_bf16(aa0, pb10, o1, 0, 0, 0);
      o1 = __builtin_amdgcn_mfma_f32_16x16x32_bf16(aa1, pb11, o1, 0, 0, 0);
      // C/D: col(l16)=pos, row(quad*4+r)=dh -> float4 store along dh
      float4 s0v; s0v.x = o0[0]; s0v.y = o0[1]; s0v.z = o0[2]; s0v.w = o0[3];
      float4 s1v; s1v.x = o1[0]; s1v.y = o1[1]; s1v.z = o1[2]; s1v.w = o1[3];
      *(float4*)(out + (size_t)(p0 + l16) * DH + mt2 * 16 + quad * 4) = s0v;
      *(float4*)(out + (size_t)(p0 + 16 + l16) * DH + mt2 * 16 + quad * 4) = s1v;
    }
  }
}

extern "C" void kernel_launch(void* const* d_in, const int* in_sizes, int n_in,
                              void* d_out, int out_size, void* d_ws, size_t ws_size,
                              hipStream_t stream) {
  const float* x  = (const float*)d_in[0];
  const float* W1 = (const float*)d_in[1];
  const float* b1 = (const float*)d_in[2];
  const float* Wq = (const float*)d_in[3];

  // workspace layout (51 MB total)
  char* w = (char*)d_ws;
  unsigned short* w1t = (unsigned short*)(w);                  // 1 MB  W1^T bf16
  unsigned short* wqt = (unsigned short*)(w + (1ull  << 20));  // 2 MB  Wq^T bf16
  unsigned short* hb  = (unsigned short*)(w + (3ull  << 20));  // 16 MB h bf16 row-major
  unsigned short* hbT = (unsigned short*)(w + (19ull << 20));  // 16 MB h bf16 transposed [DH][BS]
  unsigned short* qb  = (unsigned short*)(w + (35ull << 20));  // 16 MB q bf16 row-major

  // both weight transposes in one launch
  transpose_w_k<<<dim3(DH / 32, 48), 256, 0, stream>>>(W1, Wq, w1t, wqt);

  // h = relu(x @ W1 + b1), fused fp32->bf16; emits hb + hbT. Grid x = M-tile.
  gemm1_k<<<dim3(BS / 128, DH / 128), 256, 0, stream>>>(x, w1t, b1, hb, hbT);
  // q = h @ Wq. Grid x = M-tile.
  gemm2_k<<<dim3(BS / 128, DH / 128), 256, 0, stream>>>(hb, wqt, qb);

  attn_mfma_k<<<BS / AP, 512, 0, stream>>>(hb, hbT, qb, (float*)d_out);
}

// Round 9
// 157.713 us; speedup vs baseline: 1.0471x; 1.0471x over previous
//
#include <hip/hip_runtime.h>
#include <stdint.h>

// Problem dims: x(4,2048,512) W1(512,1024) b1(1024) Wq(1024,1024) A=16 — fp32 in, fp32 out
constexpr int BATCH = 4;
constexpr int SEQ   = 2048;
constexpr int DIN   = 512;
constexpr int DH    = 1024;
constexpr int BS    = BATCH * SEQ;  // 8192
constexpr int AP    = 32;           // attn positions per block
constexpr int AW    = 64;           // attn window rows (AP + 2*16)

typedef float  floatx4 __attribute__((ext_vector_type(4)));
typedef short  bf16x8  __attribute__((ext_vector_type(8)));

static __device__ __forceinline__ unsigned short f2bf(float f) {
  union { float f; unsigned u; } v; v.f = f;
  unsigned r = (v.u + 0x7fffu + ((v.u >> 16) & 1u)) >> 16;  // RNE
  return (unsigned short)r;
}

// async global->LDS, 16B per lane; LDS dest is wave-uniform base + lane*16
static __device__ __forceinline__ void gld_lds16(const unsigned short* g, const short* l) {
  typedef const __attribute__((address_space(1))) void* gvp;
  typedef __attribute__((address_space(3))) void* lvp;
  __builtin_amdgcn_global_load_lds((gvp)(uintptr_t)g, (lvp)(unsigned)(uintptr_t)l, 16, 0, 0);
}

// ---------------- fused weight transposes: W1(512x1024) and Wq(1024x1024) -> bf16 ^T ----
__global__ __launch_bounds__(256) void transpose_w_k(const float* __restrict__ W1,
                                                     const float* __restrict__ Wq,
                                                     unsigned short* __restrict__ w1t,
                                                     unsigned short* __restrict__ wqt) {
  __shared__ float t[32][33];
  const bool isW1 = blockIdx.y < 16;
  const float* in = isW1 ? W1 : Wq;
  unsigned short* out = isW1 ? w1t : wqt;
  const int R = isW1 ? DIN : DH;  // rows of source
  const int C = DH;
  const int r0 = (isW1 ? blockIdx.y : (blockIdx.y - 16)) * 32;
  const int c0 = blockIdx.x * 32;
  const int tx = threadIdx.x & 31, ty = threadIdx.x >> 5;  // 32 x 8
  for (int i = ty; i < 32; i += 8) t[i][tx] = in[(size_t)(r0 + i) * C + c0 + tx];
  __syncthreads();
  for (int i = ty; i < 32; i += 8) out[(size_t)(c0 + i) * R + r0 + tx] = f2bf(t[tx][i]);
}

// ---------------- GEMM1: h = relu(x @ W1 + b1), BK=64 (two BK=32 half-buffers) ----------
// Grid: blockIdx.x = M-tile (XCD L2 reuse). Emits h row-major (hb) and transposed (hbT).
__global__ __launch_bounds__(256) void gemm1_k(const float* __restrict__ X,
                                               const unsigned short* __restrict__ Bt,
                                               const float* __restrict__ bias,
                                               unsigned short* __restrict__ outB,
                                               unsigned short* __restrict__ outBT) {
  const int M = BS, N = DH, K = DIN;
  __shared__ __align__(16) short As0[128 * 32], As1[128 * 32];
  __shared__ __align__(16) short Bs0[128 * 32], Bs1[128 * 32];
  const int tid  = threadIdx.x;
  const int m0   = blockIdx.x * 128, n0 = blockIdx.y * 128;
  const int wv   = tid >> 6, lane = tid & 63;
  const int wm   = (wv >> 1) * 64, wn = (wv & 1) * 64;
  const int l16  = lane & 15, quad = lane >> 4;

  // A staging: thread covers row ar = tid>>1, cols half*16..+16 of each 32-col half
  const int ar = tid >> 1, acol = (tid & 1) * 16;
  const float* gX = X + (size_t)(m0 + ar) * K + acol;
  short* lA0 = &As0[ar * 32 + acol];
  short* lA1 = &As1[ar * 32 + acol];
  // B staging via global_load_lds (wave wv covers rows wv*32..wv*32+31, 16-row issues)
  const int ra = lane >> 2, ca = (lane & 3) * 8;
  const unsigned short* gB = Bt + (size_t)(n0 + wv * 32 + ra) * K + ca;
  const short* lB0a = &Bs0[wv * 1024];
  const short* lB0b = &Bs0[wv * 1024 + 512];
  const short* lB1a = &Bs1[wv * 1024];
  const short* lB1b = &Bs1[wv * 1024 + 512];

  floatx4 acc[4][4];
  for (int i = 0; i < 4; i++)
    for (int j = 0; j < 4; j++) acc[i][j] = {0.f, 0.f, 0.f, 0.f};

  for (int ks = 0; ks < K / 64; ++ks) {
    float4 x0 = ((const float4*)gX)[0], x1 = ((const float4*)gX)[1];
    float4 x2 = ((const float4*)gX)[2], x3 = ((const float4*)gX)[3];
    float4 x4 = ((const float4*)(gX + 32))[0], x5 = ((const float4*)(gX + 32))[1];
    float4 x6 = ((const float4*)(gX + 32))[2], x7 = ((const float4*)(gX + 32))[3];
    gX += 64;
    __align__(16) unsigned short c0[16], c1[16];
    c0[0] = f2bf(x0.x); c0[1] = f2bf(x0.y); c0[2]  = f2bf(x0.z); c0[3]  = f2bf(x0.w);
    c0[4] = f2bf(x1.x); c0[5] = f2bf(x1.y); c0[6]  = f2bf(x1.z); c0[7]  = f2bf(x1.w);
    c0[8] = f2bf(x2.x); c0[9] = f2bf(x2.y); c0[10] = f2bf(x2.z); c0[11] = f2bf(x2.w);
    c0[12] = f2bf(x3.x); c0[13] = f2bf(x3.y); c0[14] = f2bf(x3.z); c0[15] = f2bf(x3.w);
    c1[0] = f2bf(x4.x); c1[1] = f2bf(x4.y); c1[2]  = f2bf(x4.z); c1[3]  = f2bf(x4.w);
    c1[4] = f2bf(x5.x); c1[5] = f2bf(x5.y); c1[6]  = f2bf(x5.z); c1[7]  = f2bf(x5.w);
    c1[8] = f2bf(x6.x); c1[9] = f2bf(x6.y); c1[10] = f2bf(x6.z); c1[11] = f2bf(x6.w);
    c1[12] = f2bf(x7.x); c1[13] = f2bf(x7.y); c1[14] = f2bf(x7.z); c1[15] = f2bf(x7.w);
    __syncthreads();  // prev iter LDS reads done
    gld_lds16(gB, lB0a); gld_lds16(gB + 16 * K, lB0b);
    gld_lds16(gB + 32, lB1a); gld_lds16(gB + 16 * K + 32, lB1b);
    gB += 64;
    ((uint4*)lA0)[0] = ((uint4*)c0)[0];
    ((uint4*)lA0)[1] = ((uint4*)c0)[1];
    ((uint4*)lA1)[0] = ((uint4*)c1)[0];
    ((uint4*)lA1)[1] = ((uint4*)c1)[1];
    __syncthreads();  // drains vmcnt + lgkmcnt
    bf16x8 af[4], bfr[4];
    for (int i = 0; i < 4; i++)
      af[i] = *(const bf16x8*)&As0[(wm + i * 16 + l16) * 32 + quad * 8];
    for (int j = 0; j < 4; j++)
      bfr[j] = *(const bf16x8*)&Bs0[(wn + j * 16 + l16) * 32 + quad * 8];
    for (int i = 0; i < 4; i++)
      for (int j = 0; j < 4; j++)
        acc[i][j] = __builtin_amdgcn_mfma_f32_16x16x32_bf16(af[i], bfr[j], acc[i][j], 0, 0, 0);
    for (int i = 0; i < 4; i++)
      af[i] = *(const bf16x8*)&As1[(wm + i * 16 + l16) * 32 + quad * 8];
    for (int j = 0; j < 4; j++)
      bfr[j] = *(const bf16x8*)&Bs1[(wn + j * 16 + l16) * 32 + quad * 8];
    for (int i = 0; i < 4; i++)
      for (int j = 0; j < 4; j++)
        acc[i][j] = __builtin_amdgcn_mfma_f32_16x16x32_bf16(af[i], bfr[j], acc[i][j], 0, 0, 0);
  }

  // epilogue: C row = m0+wm+i*16+quad*4+r, col = n0+wn+j*16+l16 (m89-verified C/D layout)
  for (int j = 0; j < 4; j++) {
    const int col = n0 + wn + j * 16 + l16;
    const float bv = bias[col];
    for (int i = 0; i < 4; i++) {
      const int rowb = m0 + wm + i * 16 + quad * 4;
      float v[4];
      for (int r = 0; r < 4; r++) v[r] = fmaxf(acc[i][j][r] + bv, 0.f);
      for (int r = 0; r < 4; r++) outB[(size_t)(rowb + r) * N + col] = f2bf(v[r]);
      ushort4 o4; o4.x = f2bf(v[0]); o4.y = f2bf(v[1]); o4.z = f2bf(v[2]); o4.w = f2bf(v[3]);
      *(ushort4*)(outBT + (size_t)col * M + rowb) = o4;  // transposed copy for attn PV
    }
  }
}

// ---------------- GEMM2: q = h @ Wq, BK=64 (two BK=32 half-buffers) ---------------------
__global__ __launch_bounds__(256) void gemm2_k(const unsigned short* __restrict__ Ab,
                                               const unsigned short* __restrict__ Bt,
                                               unsigned short* __restrict__ outB) {
  const int N = DH, K = DH;
  __shared__ __align__(16) short As0[128 * 32], As1[128 * 32];
  __shared__ __align__(16) short Bs0[128 * 32], Bs1[128 * 32];
  const int tid  = threadIdx.x;
  const int m0   = blockIdx.x * 128, n0 = blockIdx.y * 128;  // x = M-tile (XCD streaming)
  const int wv   = tid >> 6, lane = tid & 63;
  const int wm   = (wv >> 1) * 64, wn = (wv & 1) * 64;
  const int l16  = lane & 15, quad = lane >> 4;

  const int ra = lane >> 2, ca = (lane & 3) * 8;
  const unsigned short* gA = Ab + (size_t)(m0 + wv * 32 + ra) * K + ca;
  const unsigned short* gB = Bt + (size_t)(n0 + wv * 32 + ra) * K + ca;
  const short* lA0a = &As0[wv * 1024];
  const short* lA0b = &As0[wv * 1024 + 512];
  const short* lA1a = &As1[wv * 1024];
  const short* lA1b = &As1[wv * 1024 + 512];
  const short* lB0a = &Bs0[wv * 1024];
  const short* lB0b = &Bs0[wv * 1024 + 512];
  const short* lB1a = &Bs1[wv * 1024];
  const short* lB1b = &Bs1[wv * 1024 + 512];

  floatx4 acc[4][4];
  for (int i = 0; i < 4; i++)
    for (int j = 0; j < 4; j++) acc[i][j] = {0.f, 0.f, 0.f, 0.f};

  for (int ks = 0; ks < K / 64; ++ks) {
    __syncthreads();
    gld_lds16(gA, lA0a); gld_lds16(gA + 16 * K, lA0b);
    gld_lds16(gA + 32, lA1a); gld_lds16(gA + 16 * K + 32, lA1b);
    gld_lds16(gB, lB0a); gld_lds16(gB + 16 * K, lB0b);
    gld_lds16(gB + 32, lB1a); gld_lds16(gB + 16 * K + 32, lB1b);
    gA += 64; gB += 64;
    __syncthreads();
    bf16x8 af[4], bfr[4];
    for (int i = 0; i < 4; i++)
      af[i] = *(const bf16x8*)&As0[(wm + i * 16 + l16) * 32 + quad * 8];
    for (int j = 0; j < 4; j++)
      bfr[j] = *(const bf16x8*)&Bs0[(wn + j * 16 + l16) * 32 + quad * 8];
    for (int i = 0; i < 4; i++)
      for (int j = 0; j < 4; j++)
        acc[i][j] = __builtin_amdgcn_mfma_f32_16x16x32_bf16(af[i], bfr[j], acc[i][j], 0, 0, 0);
    for (int i = 0; i < 4; i++)
      af[i] = *(const bf16x8*)&As1[(wm + i * 16 + l16) * 32 + quad * 8];
    for (int j = 0; j < 4; j++)
      bfr[j] = *(const bf16x8*)&Bs1[(wn + j * 16 + l16) * 32 + quad * 8];
    for (int i = 0; i < 4; i++)
      for (int j = 0; j < 4; j++)
        acc[i][j] = __builtin_amdgcn_mfma_f32_16x16x32_bf16(af[i], bfr[j], acc[i][j], 0, 0, 0);
  }

  for (int j = 0; j < 4; j++) {
    const int col = n0 + wn + j * 16 + l16;
    for (int i = 0; i < 4; i++) {
      const int rowb = m0 + wm + i * 16 + quad * 4;
      for (int r = 0; r < 4; r++)
        outB[(size_t)(rowb + r) * N + col] = f2bf(acc[i][j][r]);
    }
  }
}

// ---------------- barrier-light MFMA banded attention ----------------
__global__ __launch_bounds__(512) void attn_mfma_k(const unsigned short* __restrict__ hb,
                                                   const unsigned short* __restrict__ hbT,
                                                   const unsigned short* __restrict__ qb,
                                                   float* __restrict__ out) {
  __shared__ float Sf[32 * 64];                // raw scores
  __shared__ __align__(16) short Ps[32 * 72];  // softmax weights, row=pos, col=window k

  const int tid  = threadIdx.x;
  const int wave = tid >> 6, lane = tid & 63;
  const int l16  = lane & 15, quad = lane >> 4;
  const int p0   = blockIdx.x * AP;
  const int s0   = p0 & (SEQ - 1);

  for (int i = tid; i < 32 * 72 / 2; i += 512) ((unsigned*)Ps)[i] = 0;

  // ---------- QK: S[32x64], wave -> tile (mt = wave>>2, nt = wave&3) ----------
  {
    const int mt = wave >> 2, nt = wave & 3;
    const unsigned short* qp = qb + (size_t)(p0 + mt * 16 + l16) * DH + quad * 8;
    const int hrow = s0 - 16 + nt * 16 + l16;          // window row (per-lane)
    const bool hv = (hrow >= 0) && (hrow < SEQ);
    const unsigned short* hp = hb + (long long)(p0 - 16 + nt * 16 + l16) * DH + quad * 8;

    floatx4 ac[4] = {{0,0,0,0},{0,0,0,0},{0,0,0,0},{0,0,0,0}};
    const bf16x8 hz = {0,0,0,0,0,0,0,0};
    #pragma unroll
    for (int it = 0; it < 32; ++it) {                  // K = 1024
      bf16x8 qa = *(const bf16x8*)(qp + it * 32);
      bf16x8 ha = hz;
      if (hv) ha = *(const bf16x8*)(hp + it * 32);
      ac[it & 3] = __builtin_amdgcn_mfma_f32_16x16x32_bf16(qa, ha, ac[it & 3], 0, 0, 0);
    }
    floatx4 s4;
    for (int r = 0; r < 4; r++)
      s4[r] = (ac[0][r] + ac[1][r]) + (ac[2][r] + ac[3][r]);
    for (int r = 0; r < 4; r++)
      Sf[(mt * 16 + quad * 4 + r) * 64 + nt * 16 + l16] = s4[r] * (1.f / 32.f);
  }
  __syncthreads();

  // ---------- softmax over the 33 band entries jj = row..row+32 ----------
  {
    const int row = tid >> 4, k = tid & 15;  // 16 threads per row
    const float v0 = Sf[row * 64 + row + k];
    const float v1 = Sf[row * 64 + row + k + 16];
    const float v2 = (k == 0) ? Sf[row * 64 + row + 32] : -1e30f;
    float mx = fmaxf(v0, fmaxf(v1, v2));
    for (int off = 1; off < 16; off <<= 1) mx = fmaxf(mx, __shfl_xor(mx, off, 64));
    const float e0 = __expf(v0 - mx), e1 = __expf(v1 - mx);
    const float e2 = (k == 0) ? __expf(v2 - mx) : 0.f;
    float sum = e0 + e1 + e2;
    for (int off = 1; off < 16; off <<= 1) sum += __shfl_xor(sum, off, 64);
    const float inv = 1.f / sum;
    Ps[row * 72 + row + k] = f2bf(e0 * inv);
    Ps[row * 72 + row + k + 16] = f2bf(e1 * inv);
    if (k == 0) Ps[row * 72 + row + 32] = f2bf(e2 * inv);
  }
  __syncthreads();

  // ---------- PV (transposed): D[dh, pos] = Hwin^T @ P^T, both pos halves per wave ------
  {
    const bf16x8 pb00 = *(const bf16x8*)&Ps[(l16) * 72 + quad * 8];
    const bf16x8 pb01 = *(const bf16x8*)&Ps[(l16) * 72 + 32 + quad * 8];
    const bf16x8 pb10 = *(const bf16x8*)&Ps[(16 + l16) * 72 + quad * 8];
    const bf16x8 pb11 = *(const bf16x8*)&Ps[(16 + l16) * 72 + 32 + quad * 8];

    int lo = 16 - s0; if (lo < 0) lo = 0;              // valid window-k range [lo,hi)
    int hi = SEQ + 16 - s0; if (hi > AW) hi = AW;
    const bool interior = (lo == 0) && (hi == AW);

    #pragma unroll
    for (int i = 0; i < 8; ++i) {
      const int mt2 = wave * 8 + i;  // dh tile (0..63)
      const unsigned short* ap = hbT + (size_t)(mt2 * 16 + l16) * BS + (p0 - 16) + quad * 8;
      bf16x8 aa0 = *(const bf16x8*)(ap);
      bf16x8 aa1 = *(const bf16x8*)(ap + 32);
      if (!interior) {
        #pragma unroll
        for (int j = 0; j < 8; j++) {
          const int k = quad * 8 + j;
          if (k < lo || k >= hi) aa0[j] = 0;
          if (k + 32 < lo || k + 32 >= hi) aa1[j] = 0;
        }
      }
      floatx4 o0 = {0.f, 0.f, 0.f, 0.f}, o1 = {0.f, 0.f, 0.f, 0.f};
      o0 = __builtin_amdgcn_mfma_f32_16x16x32_bf16(aa0, pb00, o0, 0, 0, 0);
      o0 = __builtin_amdgcn_mfma_f32_16x16x32_bf16(aa1, pb01, o0, 0, 0, 0);
      o1 = __builtin_amdgcn_mfma_f32_16x16x32_bf16(aa0, pb10, o1, 0, 0, 0);
      o1 = __builtin_amdgcn_mfma_f32_16x16x32_bf16(aa1, pb11, o1, 0, 0, 0);
      float4 s0v; s0v.x = o0[0]; s0v.y = o0[1]; s0v.z = o0[2]; s0v.w = o0[3];
      float4 s1v; s1v.x = o1[0]; s1v.y = o1[1]; s1v.z = o1[2]; s1v.w = o1[3];
      *(float4*)(out + (size_t)(p0 + l16) * DH + mt2 * 16 + quad * 4) = s0v;
      *(float4*)(out + (size_t)(p0 + 16 + l16) * DH + mt2 * 16 + quad * 4) = s1v;
    }
  }
}

extern "C" void kernel_launch(void* const* d_in, const int* in_sizes, int n_in,
                              void* d_out, int out_size, void* d_ws, size_t ws_size,
                              hipStream_t stream) {
  const float* x  = (const float*)d_in[0];
  const float* W1 = (const float*)d_in[1];
  const float* b1 = (const float*)d_in[2];
  const float* Wq = (const float*)d_in[3];

  // workspace layout (51 MB total)
  char* w = (char*)d_ws;
  unsigned short* w1t = (unsigned short*)(w);                  // 1 MB  W1^T bf16
  unsigned short* wqt = (unsigned short*)(w + (1ull  << 20));  // 2 MB  Wq^T bf16
  unsigned short* hb  = (unsigned short*)(w + (3ull  << 20));  // 16 MB h bf16 row-major
  unsigned short* hbT = (unsigned short*)(w + (19ull << 20));  // 16 MB h bf16 transposed [DH][BS]
  unsigned short* qb  = (unsigned short*)(w + (35ull << 20));  // 16 MB q bf16 row-major

  transpose_w_k<<<dim3(DH / 32, 48), 256, 0, stream>>>(W1, Wq, w1t, wqt);

  // h = relu(x @ W1 + b1), fused fp32->bf16; emits hb + hbT. Grid x = M-tile.
  gemm1_k<<<dim3(BS / 128, DH / 128), 256, 0, stream>>>(x, w1t, b1, hb, hbT);
  // q = h @ Wq. Grid x = M-tile.
  gemm2_k<<<dim3(BS / 128, DH / 128), 256, 0, stream>>>(hb, wqt, qb);

  attn_mfma_k<<<BS / AP, 512, 0, stream>>>(hb, hbT, qb, (float*)d_out);
}